// Round 1
// 172.878 us; speedup vs baseline: 1.0225x; 1.0225x over previous
//
#include <hip/hip_runtime.h>
#include <cstdint>

#define BATCH 16
#define SEQ 2048
#define EMB 512
#define FFN 2048
#define NQ 8
#define M_TOTAL (BATCH * SEQ)   // 32768

#define BM 128
#define BN 256
#define BK 32
#define NTHREADS 512            // 8 waves: 2 (m) x 4 (n), wave tile 64x64

typedef __attribute__((ext_vector_type(8))) short short8;   // 8 bf16 (MFMA A/B frag)
typedef __attribute__((ext_vector_type(4))) float float4v;  // MFMA C/D frag
typedef __attribute__((ext_vector_type(4))) unsigned int uint4v;

// fp32 -> bf16 bits, round-to-nearest-even (finite inputs)
static __device__ __forceinline__ unsigned int f2bf(float f) {
    unsigned int u = __builtin_bit_cast(unsigned int, f);
    return (u + 0x7fffu + ((u >> 16) & 1u)) >> 16;
}
static __device__ __forceinline__ unsigned int f2bf_pk(float lo, float hi) {
    return f2bf(lo) | (f2bf(hi) << 16);
}

// ---- prep: W2 fp32 -> bf16 (row-major [EMB][FFN], K-contiguous) ----
__global__ __launch_bounds__(256) void prep_w2(const float* __restrict__ W2,
                                               unsigned int* __restrict__ w2b) {
    int idx = (blockIdx.x * 256 + threadIdx.x) * 4;
    float4 v = *(const float4*)&W2[idx];
    w2b[idx / 2]     = f2bf_pk(v.x, v.y);
    w2b[idx / 2 + 1] = f2bf_pk(v.z, v.w);
}

// Swizzled LDS tile layout: row stride 32 bf16 (64 B = 4 chunks of 16 B).
// Logical k-chunk q lives at physical chunk q ^ ((row>>1)&3) -> frag reads
// (row = base + l16, chunk = quad) cover all 32 banks per 8-lane phase.
//
// Pipeline (1 barrier per K-step): at iter k, buffers [cur] hold B(k),h(k);
// we issue B(k+1) DMA into Bsm[nxt], compute h(k+1) into Asm[nxt], run the
// 16 main MFMAs from [cur], then __syncthreads. The barrier's vmcnt(0)
// drain now waits on loads issued a full iteration earlier -> ~free.

__global__ __launch_bounds__(NTHREADS, 4) void ffq_main(
    const float* __restrict__ x,              // [M_TOTAL][EMB], cols 0..7 used
    const float* __restrict__ theta,          // [8]
    const float* __restrict__ W1,             // [FFN][8] fp32
    const unsigned short* __restrict__ w2b,   // [EMB][FFN] bf16 bits
    float* __restrict__ out)                  // [M_TOTAL][EMB]
{
    __shared__ unsigned short Asm[2][BM * BK];   // 2 x 8 KB  h tile, swizzled
    __shared__ unsigned short Bsm[2][BN * BK];   // 2 x 16 KB W2 tile, swizzled
    __shared__ unsigned short w1s[FFN * NQ];     // 32 KB whole W1 bf16 [f][j]
    // total 80 KB -> exactly 2 blocks/CU

    const int t    = threadIdx.x;
    const int m0   = blockIdx.x * BM;
    const int n0   = blockIdx.y * BN;
    const int wave = t >> 6, lane = t & 63;
    const int quad = lane >> 4, l16 = lane & 15;
    const int wm   = wave >> 2, wn = wave & 3;

    // ---- stage whole W1 -> bf16 LDS ----
#pragma unroll
    for (int i = 0; i < (FFN * NQ / 2) / NTHREADS; ++i) {   // 16 iters
        int p = i * NTHREADS + t;
        float2 v = *(const float2*)&W1[p * 2];
        *(unsigned int*)&w1s[p * 2] = f2bf_pk(v.x, v.y);
    }

    // ---- per-wave persistent Q fragment (B-operand of h-gen MFMA) ----
    // wave g owns m rows g*16..g*16+15; lane l16 holds q[g*16+l16][j=0..7]
    // in quad 0 (K slots 0..7); quads 1..3 are ZERO so K=8..31 padding adds 0.
    short8 qfrag;
    {
        int qrow = m0 + wave * 16 + l16;
        const float* xr = x + (size_t)qrow * EMB;
        float4 xa = *(const float4*)xr;
        float4 xb = *(const float4*)(xr + 4);
        uint4v uq;
        uq[0] = f2bf_pk(__cosf(2.f * xa.x + theta[0]), __cosf(2.f * xa.y + theta[1]));
        uq[1] = f2bf_pk(__cosf(2.f * xa.z + theta[2]), __cosf(2.f * xa.w + theta[3]));
        uq[2] = f2bf_pk(__cosf(2.f * xb.x + theta[4]), __cosf(2.f * xb.y + theta[5]));
        uq[3] = f2bf_pk(__cosf(2.f * xb.z + theta[6]), __cosf(2.f * xb.w + theta[7]));
        qfrag = __builtin_bit_cast(short8, uq);
        if (quad != 0) qfrag = (short8)0;
    }

    // ---- per-thread B-staging constants (chunk -> source-swizzled gaddr) ----
    const int c0 = t, c1 = NTHREADS + t;
    const int n0c0 = c0 >> 2, s0c = c0 & 3;
    const int n0c1 = c1 >> 2, s1c = c1 & 3;
    const unsigned short* gB0 =
        w2b + (size_t)(n0 + n0c0) * FFN + (s0c ^ ((n0c0 >> 1) & 3)) * 8;
    const unsigned short* gB1 =
        w2b + (size_t)(n0 + n0c1) * FFN + (s1c ^ ((n0c1 >> 1) & 3)) * 8;

    // async stage B(k0) tile into Bsm[buf] (buf must be a literal)
    auto stageB = [&](int k0, int buf) __attribute__((always_inline)) {
        __builtin_amdgcn_global_load_lds(
            (const __attribute__((address_space(1))) unsigned int*)(gB0 + k0),
            (__attribute__((address_space(3))) unsigned int*)(uintptr_t)(&Bsm[buf][c0 * 8]),
            16, 0, 0);
        __builtin_amdgcn_global_load_lds(
            (const __attribute__((address_space(1))) unsigned int*)(gB1 + k0),
            (__attribute__((address_space(3))) unsigned int*)(uintptr_t)(&Bsm[buf][c1 * 8]),
            16, 0, 0);
    };

    // h-gen for K-rows [kh, kh+32) via MFMA, relu, pack -> swizzled Asm[buf]
    const int hm   = wave * 16 + l16;
    const int hswz = (l16 >> 1) & 3;
    auto hgen = [&](int kh, int buf) __attribute__((always_inline)) {
#pragma unroll
        for (int fh = 0; fh < 2; ++fh) {
            int f = kh + fh * 16 + l16;
            short8 w1f = *(const short8*)&w1s[f * NQ];
            float4v hc = __builtin_amdgcn_mfma_f32_16x16x32_bf16(
                w1f, qfrag, (float4v)0.0f, 0, 0, 0);
            unsigned int p0 = f2bf_pk(fmaxf(hc[0], 0.f), fmaxf(hc[1], 0.f));
            unsigned int p1 = f2bf_pk(fmaxf(hc[2], 0.f), fmaxf(hc[3], 0.f));
            int qph = (fh * 2 + (quad >> 1)) ^ hswz;
            unsigned long long pk = ((unsigned long long)p1 << 32) | p0;
            *(unsigned long long*)&Asm[buf][hm * 32 + qph * 8 + (quad & 1) * 4] = pk;
        }
    };

    float4v acc[16];
#pragma unroll
    for (int i = 0; i < 16; ++i) acc[i] = (float4v)0.0f;

    // conflict-free fragment loads + 16 MFMA from buffers [buf]
    auto compute = [&](int buf) __attribute__((always_inline)) {
        short8 af[4], bfr[4];
#pragma unroll
        for (int fm = 0; fm < 4; ++fm) {
            int row = wm * 64 + fm * 16 + l16;
            int qph = quad ^ ((row >> 1) & 3);
            af[fm] = *(const short8*)&Asm[buf][row * 32 + qph * 8];
        }
#pragma unroll
        for (int fn = 0; fn < 4; ++fn) {
            int row = wn * 64 + fn * 16 + l16;
            int qph = quad ^ ((row >> 1) & 3);
            bfr[fn] = *(const short8*)&Bsm[buf][row * 32 + qph * 8];
        }
#pragma unroll
        for (int fm = 0; fm < 4; ++fm)
#pragma unroll
            for (int fn = 0; fn < 4; ++fn)
                acc[fm * 4 + fn] = __builtin_amdgcn_mfma_f32_16x16x32_bf16(
                    af[fm], bfr[fn], acc[fm * 4 + fn], 0, 0, 0);
    };

    // ---- prologue ----
    __syncthreads();        // w1s visible to all waves
    stageB(0, 0);
    hgen(0, 0);
    __syncthreads();        // vmcnt(0): B(0) landed; lgkm: h(0) visible

    // ---- pipelined main loop: 64 K-steps, 1 barrier each ----
    // pair-unrolled so the buffer parity is a compile-time constant
    for (int kt = 0; kt < 62; kt += 2) {
        stageB((kt + 1) * BK, 1);
        hgen((kt + 1) * BK, 1);
        compute(0);
        __syncthreads();

        stageB((kt + 2) * BK, 0);
        hgen((kt + 2) * BK, 0);
        compute(1);
        __syncthreads();
    }
    // kt = 62: prefetch last tile (k=63) into buf 1, compute buf 0
    stageB(63 * BK, 1);
    hgen(63 * BK, 1);
    compute(0);
    __syncthreads();
    // kt = 63: tail, compute only
    compute(1);

    // ---- epilogue: D layout col=lane&15 (n), row=quad*4+reg (m) ----
    const int om = m0 + wm * 64;
    const int on = n0 + wn * 64;
#pragma unroll
    for (int fm = 0; fm < 4; ++fm) {
#pragma unroll
        for (int fn = 0; fn < 4; ++fn) {
            float4v v = acc[fm * 4 + fn];
            int rbase = om + fm * 16 + quad * 4;
            int c     = on + fn * 16 + l16;
#pragma unroll
            for (int r = 0; r < 4; ++r)
                out[(size_t)(rbase + r) * EMB + c] = v[r];
        }
    }
}

extern "C" void kernel_launch(void* const* d_in, const int* in_sizes, int n_in,
                              void* d_out, int out_size, void* d_ws, size_t ws_size,
                              hipStream_t stream) {
    const float* x     = (const float*)d_in[0];
    const float* theta = (const float*)d_in[1];
    const float* W1    = (const float*)d_in[2];
    const float* W2    = (const float*)d_in[3];
    float* out = (float*)d_out;

    unsigned int* w2b = (unsigned int*)d_ws;   // 2 MiB of ws (bf16 bits, packed)

    prep_w2<<<(EMB * FFN) / (256 * 4), 256, 0, stream>>>(W2, w2b);

    dim3 grid(M_TOTAL / BM, EMB / BN);         // 256 x 2 = 512 blocks
    ffq_main<<<grid, NTHREADS, 0, stream>>>(x, theta, W1, (const unsigned short*)w2b, out);
}